// Round 8
// baseline (442.859 us; speedup 1.0000x reference)
//
#include <hip/hip_runtime.h>
#include <hip/hip_bf16.h>

// ---------------------------------------------------------------------------
// GraphConvEncoder: 2-layer GraphConv, transform-then-aggregate.
// GEMMs: bf16 MFMA, X-only LDS staging (1 barrier), B fragments read direct
// from pre-converted bf16 weight tables (L1-resident; R7 gemm was 2 blk/CU,
// 17% occupancy, double-staging-bound at 71us).
// Y1 = fp8(x@W1_rel^T) gathered (128B/row); Y2 = bf16(h@W2_rel^T) (128B/row).
// Aggregation: vectorized gather (uint4/lane, 8 lanes/row), 32 edges in
// flight, packed f32x2 accumulate. Past-L2 line service is the floor.
// CSR via bucketed multisplit (no global atomics, no write-amp).
// ---------------------------------------------------------------------------

#define EB 8192       // edges per block in bucket passes
#define NB_MAX 512    // max buckets (N <= 131072)

typedef __attribute__((ext_vector_type(8))) short bf16x8;
typedef __attribute__((ext_vector_type(4))) float f32x4;
typedef __attribute__((ext_vector_type(2))) float f32x2;

__device__ __forceinline__ uint pack_bf16x2(float a, float b) {
    __hip_bfloat162 p = __float22bfloat162_rn(make_float2(a, b));
    return *(uint*)&p;  // low = a, high = b
}

__device__ __forceinline__ uchar pack_fp8(float v) {
    uint p = __builtin_amdgcn_cvt_pk_fp8_f32(v, v, 0, false);
    return (uchar)(p & 0xff);
}

__device__ __forceinline__ ushort f2bf(float v) {
    __hip_bfloat16 b = __float2bfloat16(v);
    return *(ushort*)&b;
}

__device__ __forceinline__ float bflo(uint g) { return __uint_as_float(g << 16); }
__device__ __forceinline__ float bfhi(uint g) { return __uint_as_float(g & 0xffff0000u); }

// ---------------- CSR build: bucketed multisplit ----------------

__global__ __launch_bounds__(256) void bucket_hist(const int* __restrict__ dst, int E,
                                                   int NB, int* __restrict__ hist) {
    __shared__ int h[NB_MAX];
    int t = threadIdx.x;
    for (int i = t; i < NB; i += 256) h[i] = 0;
    __syncthreads();
    int e0 = blockIdx.x * EB, e1 = min(E, e0 + EB);
    for (int e = e0 + t; e < e1; e += 256) atomicAdd(&h[dst[e] >> 8], 1);
    __syncthreads();
    int* row = hist + (size_t)blockIdx.x * NB;
    for (int i = t; i < NB; i += 256) row[i] = h[i];
}

__global__ __launch_bounds__(256) void scan_blocks(int* __restrict__ hist, int NBLK,
                                                   int NB, int* __restrict__ total) {
    __shared__ int s[256];
    __shared__ int carry;
    int b = blockIdx.x, t = threadIdx.x;
    if (t == 0) carry = 0;
    __syncthreads();
    for (int start = 0; start < NBLK; start += 256) {
        int i = start + t;
        int v = (i < NBLK) ? hist[(size_t)i * NB + b] : 0;
        s[t] = v;
        __syncthreads();
        for (int off = 1; off < 256; off <<= 1) {
            int u = (t >= off) ? s[t - off] : 0;
            __syncthreads();
            s[t] += u;
            __syncthreads();
        }
        if (i < NBLK) hist[(size_t)i * NB + b] = carry + s[t] - v;
        __syncthreads();
        if (t == 255) carry += s[255];
        __syncthreads();
    }
    if (t == 0) total[b] = carry;
}

__global__ __launch_bounds__(512) void scan_total(const int* __restrict__ total, int NB,
                                                  int* __restrict__ base) {
    __shared__ int s[512];
    int t = threadIdx.x;
    int v = (t < NB) ? total[t] : 0;
    s[t] = v;
    __syncthreads();
    for (int off = 1; off < 512; off <<= 1) {
        int u = (t >= off) ? s[t - off] : 0;
        __syncthreads();
        s[t] += u;
        __syncthreads();
    }
    if (t < NB) base[t] = s[t] - v;
}

__global__ __launch_bounds__(256) void bucket_scatter(const int* __restrict__ src,
                                                      const int* __restrict__ dst, int E,
                                                      int NB, const int* __restrict__ hist,
                                                      const int* __restrict__ base,
                                                      uint* __restrict__ ebuf) {
    __shared__ int cur[NB_MAX];
    int t = threadIdx.x, blk = blockIdx.x;
    const int* row = hist + (size_t)blk * NB;
    for (int i = t; i < NB; i += 256) cur[i] = base[i] + row[i];
    __syncthreads();
    int e0 = blk * EB, e1 = min(E, e0 + EB);
    for (int e = e0 + t; e < e1; e += 256) {
        int d = dst[e];
        int p = atomicAdd(&cur[d >> 8], 1);
        ebuf[p] = ((uint)(d & 255) << 24) | (uint)src[e];
    }
}

__global__ __launch_bounds__(256) void build_csr_bucket(const uint* __restrict__ ebuf,
                                                        const int* __restrict__ base,
                                                        const int* __restrict__ total,
                                                        int NB, int N, int E,
                                                        int* __restrict__ rowptr,
                                                        int* __restrict__ col) {
    __shared__ int cnt[256];
    __shared__ int s[256];
    __shared__ int cur[256];
    int b = blockIdx.x, t = threadIdx.x;
    int e0 = base[b], e1 = e0 + total[b];
    cnt[t] = 0;
    __syncthreads();
    for (int e = e0 + t; e < e1; e += 256) atomicAdd(&cnt[ebuf[e] >> 24], 1);
    __syncthreads();
    int v = cnt[t];
    s[t] = v;
    __syncthreads();
    for (int off = 1; off < 256; off <<= 1) {
        int u = (t >= off) ? s[t - off] : 0;
        __syncthreads();
        s[t] += u;
        __syncthreads();
    }
    int start = e0 + s[t] - v;  // exclusive
    int node = (b << 8) + t;
    if (node < N) rowptr[node] = start;
    if (b == NB - 1 && t == 0) rowptr[N] = E;
    cur[t] = start;
    __syncthreads();
    for (int e = e0 + t; e < e1; e += 256) {
        uint ev = ebuf[e];
        int p = atomicAdd(&cur[ev >> 24], 1);
        col[p] = (int)(ev & 0xFFFFFFu);
    }
}

// ---------------- weight prep: fp32 -> stacked bf16 tables ----------------
// Wb1[256x128] = [W1_rel; W1_root], Wb2[128x128] = [W2_rel; W2_root]

__global__ __launch_bounds__(256) void prep_w(const float* __restrict__ W1_rel,
                                              const float* __restrict__ W1_root,
                                              const float* __restrict__ W2_rel,
                                              const float* __restrict__ W2_root,
                                              ushort* __restrict__ Wb1,
                                              ushort* __restrict__ Wb2) {
    int i = blockIdx.x * 256 + threadIdx.x;
    if (i < 32768)
        Wb1[i] = f2bf((i < 16384) ? W1_rel[i] : W1_root[i - 16384]);
    else {
        int j = i - 32768;
        if (j < 16384)
            Wb2[j] = f2bf((j < 8192) ? W2_rel[j] : W2_root[j - 8192]);
    }
}

// ---------------- MFMA dual GEMM (X-only LDS staging) ----------------
// C cols of Y = fp8|bf16(X@Wa^T), C cols of Z = bias + X@Wb^T; Wst stacked.
// Block: 256 thr = 4 waves (2x2), tile 128 rows x 128 stacked-cols, K=128
// staged once (1 barrier). B fragments direct from global bf16 Wst (32KB per
// tn-half -> L1-resident). LDS row stride 136 shorts (68 words = 4 mod 32).

#define LDK2 136

template <int C, bool A_BF16, bool Y_FP8>
__global__ __launch_bounds__(256, 4) void gemm_mfma(const void* __restrict__ Aptr,
                                                    const ushort* __restrict__ Wst,
                                                    const float* __restrict__ bias,
                                                    void* __restrict__ Yout,
                                                    float* __restrict__ Z, int n_rows) {
    __shared__ ushort Xs[128 * LDK2];

    const int t = threadIdx.x;
    const int lane = t & 63;
    const int wave = t >> 6;
    const int wm = wave >> 1, wn = wave & 1;
    const int row0 = blockIdx.x * 128;
    const int tn = blockIdx.y;
    const int fr = lane & 15;
    const int quad = lane >> 4;

    if (A_BF16) {
        const ushort* A = (const ushort*)Aptr;
#pragma unroll
        for (int j = 0; j < 8; ++j) {
            int f = j * 256 + t;          // 2048 uint4 chunks (16/row)
            int r = f >> 4, c = f & 15;
            int grow = row0 + r;
            uint4 v = make_uint4(0u, 0u, 0u, 0u);
            if (grow < n_rows) v = *(const uint4*)(A + (size_t)grow * 128 + c * 8);
            *(uint4*)(&Xs[r * LDK2 + c * 8]) = v;
        }
    } else {
        const float* A = (const float*)Aptr;
#pragma unroll
        for (int j = 0; j < 16; ++j) {
            int f = j * 256 + t;          // 4096 float4 chunks (32/row)
            int r = f >> 5, c = f & 31;
            int grow = row0 + r;
            float4 v = make_float4(0.f, 0.f, 0.f, 0.f);
            if (grow < n_rows) v = *(const float4*)(A + (size_t)grow * 128 + c * 4);
            uint2 u;
            u.x = pack_bf16x2(v.x, v.y);
            u.y = pack_bf16x2(v.z, v.w);
            *(uint2*)(&Xs[r * LDK2 + c * 4]) = u;
        }
    }
    __syncthreads();

    f32x4 acc[4][4];
#pragma unroll
    for (int i = 0; i < 4; i++)
#pragma unroll
        for (int j = 0; j < 4; j++) acc[i][j] = (f32x4){0.f, 0.f, 0.f, 0.f};

#pragma unroll
    for (int ks = 0; ks < 4; ++ks) {
        bf16x8 a[4], b[4];
#pragma unroll
        for (int nt = 0; nt < 4; ++nt)
            b[nt] = *(const bf16x8*)(Wst +
                     (size_t)(tn * 128 + wn * 64 + nt * 16 + fr) * 128 +
                     ks * 32 + quad * 8);
#pragma unroll
        for (int mt = 0; mt < 4; ++mt)
            a[mt] = *(const bf16x8*)(&Xs[(wm * 64 + mt * 16 + fr) * LDK2 +
                                         ks * 32 + quad * 8]);
#pragma unroll
        for (int mt = 0; mt < 4; ++mt)
#pragma unroll
            for (int nt = 0; nt < 4; ++nt)
                acc[mt][nt] = __builtin_amdgcn_mfma_f32_16x16x32_bf16(
                    a[mt], b[nt], acc[mt][nt], 0, 0, 0);
    }

    // C/D layout: col = lane&15, row = quad*4 + reg
#pragma unroll
    for (int nt = 0; nt < 4; ++nt) {
        int gcol = tn * 128 + wn * 64 + nt * 16 + fr;
        if (gcol < C) {
#pragma unroll
            for (int mt = 0; mt < 4; ++mt) {
#pragma unroll
                for (int r = 0; r < 4; ++r) {
                    int grow = row0 + wm * 64 + mt * 16 + quad * 4 + r;
                    if (grow < n_rows) {
                        if (Y_FP8)
                            ((uchar*)Yout)[(size_t)grow * C + gcol] =
                                pack_fp8(acc[mt][nt][r]);
                        else
                            ((ushort*)Yout)[(size_t)grow * C + gcol] =
                                f2bf(acc[mt][nt][r]);
                    }
                }
            }
        } else {
            float bv = bias[gcol - C];
#pragma unroll
            for (int mt = 0; mt < 4; ++mt) {
#pragma unroll
                for (int r = 0; r < 4; ++r) {
                    int grow = row0 + wm * 64 + mt * 16 + quad * 4 + r;
                    if (grow < n_rows)
                        Z[(size_t)grow * C + (gcol - C)] = acc[mt][nt][r] + bv;
                }
            }
        }
    }
}

// ---------------- aggregation (vectorized gather) ----------------
// layer 1: one wave per node. Y1 row = 128 fp8 B. Lane L: edge-slot L>>3,
// 16B chunk (L&7). 32 edges (4 uint4) in flight; packed f32x2 accumulate.

__device__ __forceinline__ void acc_fp8x16(f32x2* acc2, uint4 v) {
    acc2[0] += __builtin_amdgcn_cvt_pk_f32_fp8(v.x, false);
    acc2[1] += __builtin_amdgcn_cvt_pk_f32_fp8(v.x, true);
    acc2[2] += __builtin_amdgcn_cvt_pk_f32_fp8(v.y, false);
    acc2[3] += __builtin_amdgcn_cvt_pk_f32_fp8(v.y, true);
    acc2[4] += __builtin_amdgcn_cvt_pk_f32_fp8(v.z, false);
    acc2[5] += __builtin_amdgcn_cvt_pk_f32_fp8(v.z, true);
    acc2[6] += __builtin_amdgcn_cvt_pk_f32_fp8(v.w, false);
    acc2[7] += __builtin_amdgcn_cvt_pk_f32_fp8(v.w, true);
}

__global__ __launch_bounds__(256) void agg_relu_l1(const uchar* __restrict__ Y1,
                                                   const float* __restrict__ Z1,
                                                   const int* __restrict__ rowptr,
                                                   const int* __restrict__ col,
                                                   ushort* __restrict__ h, int n_nodes) {
    int node = (blockIdx.x * 256 + threadIdx.x) >> 6;
    if (node >= n_nodes) return;
    int lane = threadIdx.x & 63;
    int sub = lane >> 3;   // edge slot within group of 8
    int cg  = lane & 7;    // channel group: channels cg*16 .. +15
    int beg = rowptr[node], end = rowptr[node + 1];
    f32x2 acc2[8];
#pragma unroll
    for (int i = 0; i < 8; i++) acc2[i] = (f32x2){0.f, 0.f};

    int e = beg;
    for (; e + 32 <= end; e += 32) {
        int s0 = col[e + sub];
        int s1 = col[e + 8 + sub];
        int s2 = col[e + 16 + sub];
        int s3 = col[e + 24 + sub];
        uint4 v0 = *(const uint4*)(Y1 + (size_t)s0 * 128 + cg * 16);
        uint4 v1 = *(const uint4*)(Y1 + (size_t)s1 * 128 + cg * 16);
        uint4 v2 = *(const uint4*)(Y1 + (size_t)s2 * 128 + cg * 16);
        uint4 v3 = *(const uint4*)(Y1 + (size_t)s3 * 128 + cg * 16);
        acc_fp8x16(acc2, v0);
        acc_fp8x16(acc2, v1);
        acc_fp8x16(acc2, v2);
        acc_fp8x16(acc2, v3);
    }
    for (; e < end; e += 8) {  // masked tail groups
        int ee = e + sub;
        uint4 v = make_uint4(0u, 0u, 0u, 0u);
        if (ee < end) v = *(const uint4*)(Y1 + (size_t)col[ee] * 128 + cg * 16);
        acc_fp8x16(acc2, v);
    }

    float acc[16];
#pragma unroll
    for (int i = 0; i < 8; i++) { acc[2 * i] = acc2[i][0]; acc[2 * i + 1] = acc2[i][1]; }
#pragma unroll
    for (int off = 8; off < 64; off <<= 1)
#pragma unroll
        for (int i = 0; i < 16; i++) acc[i] += __shfl_xor(acc[i], off, 64);

    if (sub == 0) {  // lanes 0..7: channels cg*16..+15
        const float4* zp = (const float4*)(Z1 + (size_t)node * 128 + cg * 16);
        uint o[8];
#pragma unroll
        for (int q = 0; q < 4; ++q) {
            float4 z = zp[q];
            float r0 = acc[q * 4 + 0] + z.x;
            float r1 = acc[q * 4 + 1] + z.y;
            float r2 = acc[q * 4 + 2] + z.z;
            float r3 = acc[q * 4 + 3] + z.w;
            r0 = r0 > 0.f ? r0 : 0.f;
            r1 = r1 > 0.f ? r1 : 0.f;
            r2 = r2 > 0.f ? r2 : 0.f;
            r3 = r3 > 0.f ? r3 : 0.f;
            o[q * 2 + 0] = pack_bf16x2(r0, r1);
            o[q * 2 + 1] = pack_bf16x2(r2, r3);
        }
        uint* hp = (uint*)(h + (size_t)node * 128) + cg * 8;
        *(uint4*)(hp + 0) = make_uint4(o[0], o[1], o[2], o[3]);
        *(uint4*)(hp + 4) = make_uint4(o[4], o[5], o[6], o[7]);
    }
}

// layer 2: one wave per node. Y2 row = 64 bf16 = 128 B. Same structure.

__device__ __forceinline__ void acc_bf16x8(float* acc, uint4 v) {
    acc[0] += bflo(v.x);
    acc[1] += bfhi(v.x);
    acc[2] += bflo(v.y);
    acc[3] += bfhi(v.y);
    acc[4] += bflo(v.z);
    acc[5] += bfhi(v.z);
    acc[6] += bflo(v.w);
    acc[7] += bfhi(v.w);
}

__global__ __launch_bounds__(256) void agg_l2(const ushort* __restrict__ Y2,
                                              const float* __restrict__ Z2,
                                              const int* __restrict__ rowptr,
                                              const int* __restrict__ col,
                                              float* __restrict__ out, int n_nodes) {
    int node = (blockIdx.x * 256 + threadIdx.x) >> 6;
    if (node >= n_nodes) return;
    int lane = threadIdx.x & 63;
    int sub = lane >> 3;
    int cg  = lane & 7;   // channels cg*8 .. +7
    int beg = rowptr[node], end = rowptr[node + 1];
    float acc[8];
#pragma unroll
    for (int i = 0; i < 8; i++) acc[i] = 0.f;

    int e = beg;
    for (; e + 32 <= end; e += 32) {
        int s0 = col[e + sub];
        int s1 = col[e + 8 + sub];
        int s2 = col[e + 16 + sub];
        int s3 = col[e + 24 + sub];
        uint4 v0 = *(const uint4*)(Y2 + (size_t)s0 * 64 + cg * 8);
        uint4 v1 = *(const uint4*)(Y2 + (size_t)s1 * 64 + cg * 8);
        uint4 v2 = *(const uint4*)(Y2 + (size_t)s2 * 64 + cg * 8);
        uint4 v3 = *(const uint4*)(Y2 + (size_t)s3 * 64 + cg * 8);
        acc_bf16x8(acc, v0);
        acc_bf16x8(acc, v1);
        acc_bf16x8(acc, v2);
        acc_bf16x8(acc, v3);
    }
    for (; e < end; e += 8) {
        int ee = e + sub;
        uint4 v = make_uint4(0u, 0u, 0u, 0u);
        if (ee < end) v = *(const uint4*)(Y2 + (size_t)col[ee] * 64 + cg * 8);
        acc_bf16x8(acc, v);
    }

#pragma unroll
    for (int off = 8; off < 64; off <<= 1)
#pragma unroll
        for (int i = 0; i < 8; i++) acc[i] += __shfl_xor(acc[i], off, 64);

    if (sub == 0) {  // lanes 0..7: channels cg*8..+7
        const float4* zp = (const float4*)(Z2 + (size_t)node * 64 + cg * 8);
        float4 z0 = zp[0], z1 = zp[1];
        float4 o0 = {acc[0] + z0.x, acc[1] + z0.y, acc[2] + z0.z, acc[3] + z0.w};
        float4 o1 = {acc[4] + z1.x, acc[5] + z1.y, acc[6] + z1.z, acc[7] + z1.w};
        float4* op = (float4*)(out + (size_t)node * 64 + cg * 8);
        op[0] = o0;
        op[1] = o1;
    }
}

// ---------------- launch ----------------

extern "C" void kernel_launch(void* const* d_in, const int* in_sizes, int n_in,
                              void* d_out, int out_size, void* d_ws, size_t ws_size,
                              hipStream_t stream) {
    const float* x       = (const float*)d_in[0];
    const int*   ei      = (const int*)d_in[1];
    const float* W1_rel  = (const float*)d_in[2];
    const float* b1      = (const float*)d_in[3];
    const float* W1_root = (const float*)d_in[4];
    const float* W2_rel  = (const float*)d_in[5];
    const float* b2      = (const float*)d_in[6];
    const float* W2_root = (const float*)d_in[7];
    float* out = (float*)d_out;

    const int N = in_sizes[0] / 128;
    const int E = in_sizes[1] / 2;
    const int* srcA = ei;
    const int* dstA = ei + E;
    const int NB   = (N + 255) >> 8;
    const int NBLK = (E + EB - 1) / EB;

    char* ws = (char*)d_ws;
    size_t cur = 0;
    auto alloc = [&](size_t bytes) -> void* {
        size_t o = cur;
        cur = (cur + bytes + 511) & ~(size_t)511;
        return (void*)(ws + o);
    };
    uchar*  Y1  = (uchar*)alloc((size_t)N * 128);        // fp8
    float*  Z1  = (float*)alloc((size_t)N * 128 * 4);
    ushort* h   = (ushort*)alloc((size_t)N * 128 * 2);   // bf16
    ushort* Y2  = (ushort*)alloc((size_t)N * 64 * 2);    // bf16
    float*  Z2  = (float*)alloc((size_t)N * 64 * 4);
    ushort* Wb1 = (ushort*)alloc(32768 * 2);
    ushort* Wb2 = (ushort*)alloc(16384 * 2);
    int* rowptr = (int*)alloc((size_t)(N + 1) * 4);
    int* colA   = (int*)alloc((size_t)E * 4);
    int* hist   = (int*)alloc((size_t)NBLK * NB * 4);
    int* btotal = (int*)alloc((size_t)NB_MAX * 4);
    int* bbase  = (int*)alloc((size_t)NB_MAX * 4);
    uint* ebuf  = (uint*)h;  // alias: ebuf dead before h is written

    prep_w<<<192, 256, 0, stream>>>(W1_rel, W1_root, W2_rel, W2_root, Wb1, Wb2);
    bucket_hist<<<NBLK, 256, 0, stream>>>(dstA, E, NB, hist);
    scan_blocks<<<NB, 256, 0, stream>>>(hist, NBLK, NB, btotal);
    scan_total<<<1, 512, 0, stream>>>(btotal, NB, bbase);
    bucket_scatter<<<NBLK, 256, 0, stream>>>(srcA, dstA, E, NB, hist, bbase, ebuf);
    build_csr_bucket<<<NB, 256, 0, stream>>>(ebuf, bbase, btotal, NB, N, E, rowptr, colA);

    const int gblk = (N + 127) / 128;
    gemm_mfma<128, false, true><<<dim3(gblk, 2), 256, 0, stream>>>(
        x, Wb1, b1, Y1, Z1, N);
    agg_relu_l1<<<(N + 3) / 4, 256, 0, stream>>>(Y1, Z1, rowptr, colA, h, N);
    gemm_mfma<64, true, false><<<dim3(gblk, 1), 256, 0, stream>>>(
        h, Wb2, b2, Y2, Z2, N);
    agg_l2<<<(N + 3) / 4, 256, 0, stream>>>(Y2, Z2, rowptr, colA, out, N);
}